// Round 5
// baseline (69.981 us; speedup 1.0000x reference)
//
#include <hip/hip_runtime.h>
#include <math.h>

#define CC 3
#define HH 720
#define WW 1280
#define HW (HH * WW)

// 2D tiling: 64 wide x 4 tall per block (256 threads, 1 px/thread)
#define TW 64
#define TH 4
#define GX (WW / TW)    // 20
#define GY (HH / TH)    // 180
#define NWG (GX * GY)   // 3600 (div by 8 -> XCD swizzle)

// LDS window: flow floor in [-R, R] handled fast
#define R 16
#define WROWS 43        // 2R + 11  (rows h0-19 .. h0+23)
#define WCOLS 103       // 2R + 71  (cols w0-19 .. w0+83)
#define WSTR 120        // halfs per row (240 B: 16B-multiple, bank-rotating)
#define ROWB 240        // bytes per row
#define CPH (WROWS * WSTR)      // halfs per copy   = 5160
#define CHB (2 * CPH * 2)       // bytes per channel (2 copies) = 20640
#define NCHUNK 13               // 13 chunks of 8 cover 103 cols

typedef float f4 __attribute__((ext_vector_type(4), aligned(4)));
typedef _Float16 h8 __attribute__((ext_vector_type(8), aligned(4)));
typedef _Float16 ha8 __attribute__((ext_vector_type(8), aligned(16)));
typedef _Float16 h2a __attribute__((ext_vector_type(2), aligned(4)));

// cos(pi*k/8), sin(pi*k/8), (-1)^k for k = -3..4 (index j = k+3)
__constant__ float COSK[8] = {0.38268343f, 0.70710678f, 0.92387953f, 1.0f,
                              0.92387953f, 0.70710678f, 0.38268343f, 0.0f};
__constant__ float SINK[8] = {-0.92387953f, -0.70710678f, -0.38268343f, 0.0f,
                              0.38268343f, 0.70710678f, 0.92387953f, 1.0f};
__constant__ float SGNK[8] = {-1.0f, 1.0f, -1.0f, 1.0f, -1.0f, 1.0f, -1.0f, 1.0f};

__device__ __forceinline__ void sinc_weights(float s, float* wgt) {
    const float PI = 3.14159265358979f;
    float sp = __sinf(PI * s);
    float s8, c8;
    __sincosf(PI * s * 0.125f, &s8, &c8);
#pragma unroll
    for (int j = 0; j < 8; ++j) {
        float t = s - (float)(j - 3);
        float win = c8 * COSK[j] + s8 * SINK[j];
        float r = (t == 0.0f) ? 1.0f : __fdividef(sp * SGNK[j], PI * t);
        wgt[j] = win * r;
    }
}

__device__ __forceinline__ float dot8(h8 v, const float* cx) {
    float r = (float)v[0] * cx[0];
    r = fmaf((float)v[1], cx[1], r);
    r = fmaf((float)v[2], cx[2], r);
    r = fmaf((float)v[3], cx[3], r);
    r = fmaf((float)v[4], cx[4], r);
    r = fmaf((float)v[5], cx[5], r);
    r = fmaf((float)v[6], cx[6], r);
    r = fmaf((float)v[7], cx[7], r);
    return r;
}

// exact f32 global path for out-of-window pixels (rare) — full clamping
__device__ __forceinline__ void pixel_slow(const float* __restrict__ x,
                                           int bx, int by,
                                           const float* cxw, const float* cyw,
                                           float& r0, float& r1, float& r2) {
    int xcl[8];
#pragma unroll
    for (int j = 0; j < 8; ++j) xcl[j] = min(max(bx + (j - 3), 0), WW - 1);
    r0 = 0.f; r1 = 0.f; r2 = 0.f;
#pragma unroll
    for (int i = 0; i < 8; ++i) {
        int o = min(max(by + (i - 3), 0), HH - 1) * WW;
        float cyi = cyw[i];
        const float* p0 = x + o;
        const float* p1 = p0 + HW;
        const float* p2 = p1 + HW;
        float rs0 = 0.f, rs1 = 0.f, rs2 = 0.f;
#pragma unroll
        for (int j = 0; j < 8; ++j) {
            float cj = cxw[j];
            rs0 = fmaf(p0[xcl[j]], cj, rs0);
            rs1 = fmaf(p1[xcl[j]], cj, rs1);
            rs2 = fmaf(p2[xcl[j]], cj, rs2);
        }
        r0 = fmaf(cyi, rs0, r0);
        r1 = fmaf(cyi, rs1, r1);
        r2 = fmaf(cyi, rs2, r2);
    }
}

__global__ __launch_bounds__(256) void warp_kernel(const float* __restrict__ x,
                                                   const float* __restrict__ flow,
                                                   float* __restrict__ out) {
    // layout: halfs, ((ch*2 + parity)*WROWS + row)*WSTR + slot
    // copy A (parity 0): element k at slot k (row base 16B-aligned)
    // copy B (parity 1): element k at byte rowbase + 2k + 2  (odd k -> 4B-aligned)
    __shared__ _Float16 lds[CC * 2 * CPH];   // 61920 B

    int bid = blockIdx.x;
    int swz = (bid & 7) * (NWG / 8) + (bid >> 3);
    int tx = swz % GX;
    int ty = swz / GX;
    int w0 = tx * TW;
    int h0 = ty * TH;

    // ---------- stage window ----------
    if (tx >= 1 && tx <= GX - 2) {
        // interior columns: vectorized staging
        for (int task = threadIdx.x; task < CC * WROWS * NCHUNK; task += 256) {
            int c = task % NCHUNK;
            int rr = task / NCHUNK;
            int j = rr % WROWS;
            int ch = rr / WROWS;
            int grow = min(max(h0 - 19 + j, 0), HH - 1);
            const float* src = x + ch * HW + grow * WW + (w0 - 19) + 8 * c;
            f4 va = *(const f4*)src;
            f4 vb = *(const f4*)(src + 4);
            _Float16 v0 = (_Float16)va.x, v1 = (_Float16)va.y,
                     v2 = (_Float16)va.z, v3 = (_Float16)va.w;
            _Float16 v4 = (_Float16)vb.x, v5 = (_Float16)vb.y,
                     v6 = (_Float16)vb.z, v7 = (_Float16)vb.w;
            int rowA = (ch * 2 * WROWS + j) * WSTR;
            int E = 8 * c;
            *(ha8*)(lds + rowA + E) = (ha8){v0, v1, v2, v3, v4, v5, v6, v7};
            _Float16* pB = lds + rowA + CPH + E;   // copy B row base + E
            pB[1] = v0;                            // slot E+1  (element E)
            *(h2a*)(pB + 2) = (h2a){v1, v2};
            *(h2a*)(pB + 4) = (h2a){v3, v4};
            *(h2a*)(pB + 6) = (h2a){v5, v6};
            pB[8] = v7;                            // element E+7
        }
    } else {
        // border columns: scalar clamped staging
        for (int task = threadIdx.x; task < CC * WROWS * WCOLS; task += 256) {
            int k = task % WCOLS;
            int rr = task / WCOLS;
            int j = rr % WROWS;
            int ch = rr / WROWS;
            int grow = min(max(h0 - 19 + j, 0), HH - 1);
            int gcol = min(max(w0 - 19 + k, 0), WW - 1);
            _Float16 v = (_Float16)x[ch * HW + grow * WW + gcol];
            int rowA = (ch * 2 * WROWS + j) * WSTR;
            lds[rowA + k] = v;
            lds[rowA + CPH + k + 1] = v;
        }
    }
    __syncthreads();

    // ---------- per-pixel warp ----------
    int w = w0 + (threadIdx.x & 63);
    int h = h0 + (threadIdx.x >> 6);
    int idx = h * WW + w;

    float fx = flow[idx];
    float fy = flow[HW + idx];
    float rfx = floorf(fx), rfy = floorf(fy);
    float sx = fx - rfx, sy = fy - rfy;
    int ix = (int)rfx, iy = (int)rfy;

    float cxw[8], cyw[8];
    sinc_weights(sx, cxw);
    sinc_weights(sy, cyw);

    float r0, r1, r2;
    bool fast = (ix >= -R) && (ix <= R) && (iy >= -R) && (iy <= R);

    if (fast) {
        int k0 = (w - w0) + ix + R;   // 0..95
        int J0 = (h - h0) + iy + R;   // 0..35 ; tap i uses row J0+i (<=42)
        int p = k0 & 1;
        int slot0 = k0 + p;           // even
        const char* base = (const char*)lds +
            (size_t)(((p * WROWS) + J0) * WSTR + slot0) * 2;
        r0 = r1 = r2 = 0.f;
#pragma unroll
        for (int i = 0; i < 8; ++i) {
            h8 v0 = *(const h8*)(base + i * ROWB);
            h8 v1 = *(const h8*)(base + i * ROWB + CHB);
            h8 v2 = *(const h8*)(base + i * ROWB + 2 * CHB);
            float cyi = cyw[i];
            r0 = fmaf(cyi, dot8(v0, cxw), r0);
            r1 = fmaf(cyi, dot8(v1, cxw), r1);
            r2 = fmaf(cyi, dot8(v2, cxw), r2);
        }
    } else {
        pixel_slow(x, w + ix, h + iy, cxw, cyw, r0, r1, r2);
    }

    out[idx] = r0;
    out[HW + idx] = r1;
    out[2 * HW + idx] = r2;
}

extern "C" void kernel_launch(void* const* d_in, const int* in_sizes, int n_in,
                              void* d_out, int out_size, void* d_ws, size_t ws_size,
                              hipStream_t stream) {
    const float* x = (const float*)d_in[0];
    const float* flow = (const float*)d_in[1];
    float* out = (float*)d_out;
    warp_kernel<<<NWG, 256, 0, stream>>>(x, flow, out);
}

// Round 6
// 53.930 us; speedup vs baseline: 1.2976x; 1.2976x over previous
//
#include <hip/hip_runtime.h>
#include <math.h>

#define CC 3
#define HH 720
#define WW 1280
#define HW (HH * WW)

// sorted-gather tiling: 64 wide x 16 tall per block, 1024 threads, 1 px/thread
#define TW 64
#define TH 16
#define GX (WW / TW)    // 20
#define GY (HH / TH)    // 45
#define NWG (GX * GY)   // 900

// fp16 workspace: copy A at even base, copy B at odd base (+1): any 8-tap
// window is ONE 4B-aligned global dwordx4. (proven round 3)
#define SW 1288
#define PLANE (HH * SW)
#define WS_HALFS (6 * PLANE + 8)
#define WS_BYTES ((size_t)WS_HALFS * 2)

#define RMAX 16         // |floor(flow)| <= RMAX handled fast
#define NKEY 97         // 48 by-values * 2 parity + slow bucket

typedef float f4 __attribute__((ext_vector_type(4), aligned(4)));
typedef _Float16 h8 __attribute__((ext_vector_type(8), aligned(4)));
typedef _Float16 h2v __attribute__((ext_vector_type(2)));

#if __has_builtin(__builtin_amdgcn_fdot2)
#define HAVE_FDOT2 1
#endif

// cos(pi*k/8), sin(pi*k/8), (-1)^k for k = -3..4 (index j = k+3)
__constant__ float COSK[8] = {0.38268343f, 0.70710678f, 0.92387953f, 1.0f,
                              0.92387953f, 0.70710678f, 0.38268343f, 0.0f};
__constant__ float SINK[8] = {-0.92387953f, -0.70710678f, -0.38268343f, 0.0f,
                              0.38268343f, 0.70710678f, 0.92387953f, 1.0f};
__constant__ float SGNK[8] = {-1.0f, 1.0f, -1.0f, 1.0f, -1.0f, 1.0f, -1.0f, 1.0f};

__device__ __forceinline__ void sinc_weights(float s, float* wgt) {
    const float PI = 3.14159265358979f;
    float sp = __sinf(PI * s);
    float s8, c8;
    __sincosf(PI * s * 0.125f, &s8, &c8);
#pragma unroll
    for (int j = 0; j < 8; ++j) {
        float t = s - (float)(j - 3);
        float win = c8 * COSK[j] + s8 * SINK[j];
        float r = (t == 0.0f) ? 1.0f : __fdividef(sp * SGNK[j], PI * t);
        wgt[j] = win * r;
    }
}

__device__ __forceinline__ float dot8f(h8 v, const h2v* cw) {
#ifdef HAVE_FDOT2
    h2v* p = (h2v*)&v;
    float a = __builtin_amdgcn_fdot2(p[0], cw[0], 0.0f, false);
    a = __builtin_amdgcn_fdot2(p[1], cw[1], a, false);
    a = __builtin_amdgcn_fdot2(p[2], cw[2], a, false);
    a = __builtin_amdgcn_fdot2(p[3], cw[3], a, false);
    return a;
#else
    float r = 0.f;
#pragma unroll
    for (int j = 0; j < 8; ++j)
        r = fmaf((float)v[j], (float)cw[j >> 1][j & 1], r);
    return r;
#endif
}

// x (f32 CHW) -> two fp16 copies in ws (even-base and odd-base)
__global__ __launch_bounds__(256) void conv_kernel(const float* __restrict__ x,
                                                   _Float16* __restrict__ ws) {
    int tid = blockIdx.x * blockDim.x + threadIdx.x;
    if (tid >= CC * HH * (WW / 4)) return;
    int k4 = tid % (WW / 4);
    int rest = tid / (WW / 4);
    int k = k4 * 4;
    f4 v = *(const f4*)(x + rest * WW + k);
    int dst = rest * SW + k;
    _Float16 a = (_Float16)v.x, b = (_Float16)v.y,
             c = (_Float16)v.z, d = (_Float16)v.w;
    typedef _Float16 h4 __attribute__((ext_vector_type(4), aligned(8)));
    *(h4*)(ws + dst) = (h4){a, b, c, d};
    _Float16* wb = ws + 3 * PLANE + 1 + dst;
    wb[0] = a; wb[1] = b; wb[2] = c; wb[3] = d;
}

// exact f32 global path (border / large-flow pixels) — full clamping
__device__ __forceinline__ void pixel_slow(const float* __restrict__ x,
                                           int bx, int by,
                                           const float* cxw, const float* cyw,
                                           float& r0, float& r1, float& r2) {
    int xcl[8];
#pragma unroll
    for (int j = 0; j < 8; ++j) xcl[j] = min(max(bx + (j - 3), 0), WW - 1);
    r0 = 0.f; r1 = 0.f; r2 = 0.f;
#pragma unroll
    for (int i = 0; i < 8; ++i) {
        int o = min(max(by + (i - 3), 0), HH - 1) * WW;
        float cyi = cyw[i];
        const float* p0 = x + o;
        const float* p1 = p0 + HW;
        const float* p2 = p1 + HW;
        float rs0 = 0.f, rs1 = 0.f, rs2 = 0.f;
#pragma unroll
        for (int j = 0; j < 8; ++j) {
            float cj = cxw[j];
            rs0 = fmaf(p0[xcl[j]], cj, rs0);
            rs1 = fmaf(p1[xcl[j]], cj, rs1);
            rs2 = fmaf(p2[xcl[j]], cj, rs2);
        }
        r0 = fmaf(cyi, rs0, r0);
        r1 = fmaf(cyi, rs1, r1);
        r2 = fmaf(cyi, rs2, r2);
    }
}

__global__ __launch_bounds__(1024) void warp_kernel(const float* __restrict__ x,
                                                    const float* __restrict__ flow,
                                                    const _Float16* __restrict__ hx,
                                                    float* __restrict__ out) {
    __shared__ float sfx[1024], sfy[1024];
    __shared__ unsigned short sid[1024];
    __shared__ int HIST[128], SC[128], CUR[128];

    int tid = threadIdx.x;

    // bijective XCD swizzle (NWG=900: q=112, r=4)
    int bid = blockIdx.x;
    const int q = NWG / 8, r = NWG % 8;
    int xcd = bid & 7;
    int swz = (xcd < r ? xcd * (q + 1) : r * (q + 1) + (xcd - r) * q) + (bid >> 3);
    int tx = swz % GX;
    int ty = swz / GX;
    int w0 = tx * TW;
    int h0 = ty * TH;

    if (tid < 128) HIST[tid] = 0;
    __syncthreads();

    // phase 1: load flow (coalesced), compute sort key
    int w = w0 + (tid & 63);
    int h = h0 + (tid >> 6);
    int idx = h * WW + w;
    float fx = flow[idx];
    float fy = flow[HW + idx];
    sfx[tid] = fx;
    sfy[tid] = fy;
    {
        float rfx = floorf(fx), rfy = floorf(fy);
        int ix = (int)rfx, iy = (int)rfy;
        int s = w + ix - 3;
        int by = h + iy;
        bool fast = (iy >= -RMAX) && (iy <= RMAX) && (s >= 0) && (s <= WW - 8);
        int key = fast ? ((by - (h0 - RMAX)) * 2 + (s & 1)) : (NKEY - 1);
        atomicAdd(&HIST[key], 1);
    }
    __syncthreads();

    // phase 2: exclusive scan of 97 buckets (Hillis-Steele over 128)
    if (tid < 128) SC[tid] = HIST[tid];
    __syncthreads();
    for (int d = 1; d < 128; d <<= 1) {
        int v = 0;
        if (tid < 128 && tid >= d) v = SC[tid - d];
        __syncthreads();
        if (tid < 128) SC[tid] += v;
        __syncthreads();
    }
    if (tid < 128) CUR[tid] = SC[tid] - HIST[tid];
    __syncthreads();

    // phase 3: scatter pixel ids into sorted order
    {
        float rfx = floorf(fx), rfy = floorf(fy);
        int ix = (int)rfx, iy = (int)rfy;
        int s = w + ix - 3;
        int by = h + iy;
        bool fast = (iy >= -RMAX) && (iy <= RMAX) && (s >= 0) && (s <= WW - 8);
        int key = fast ? ((by - (h0 - RMAX)) * 2 + (s & 1)) : (NKEY - 1);
        int pos = atomicAdd(&CUR[key], 1);
        sid[pos] = (unsigned short)tid;
    }
    __syncthreads();

    // phase 4: process sorted pixel (lanes now share rows -> shared lines)
    int me = sid[tid];
    float mfx = sfx[me], mfy = sfy[me];
    int mw = w0 + (me & 63);
    int mh = h0 + (me >> 6);
    float rfx = floorf(mfx), rfy = floorf(mfy);
    float sx = mfx - rfx, sy = mfy - rfy;
    int ix = (int)rfx, iy = (int)rfy;
    int s = mw + ix - 3;
    int by = mh + iy;
    bool fast = (iy >= -RMAX) && (iy <= RMAX) && (s >= 0) && (s <= WW - 8);

    float cxw[8], cyw[8];
    sinc_weights(sx, cxw);
    sinc_weights(sy, cyw);

    float r0, r1, r2;
    if (fast) {
        h2v cwp[4];
#pragma unroll
        for (int j = 0; j < 4; ++j)
            cwp[j] = (h2v){(_Float16)cxw[2 * j], (_Float16)cxw[2 * j + 1]};
        const _Float16* hp = hx + ((s & 1) ? (3 * PLANE + 1) : 0) + s;
        int ro[8];
#pragma unroll
        for (int i = 0; i < 8; ++i)
            ro[i] = min(max(by + (i - 3), 0), HH - 1) * SW;
        r0 = r1 = r2 = 0.f;
#pragma unroll
        for (int i = 0; i < 8; ++i) {
            h8 v0 = *(const h8*)(hp + ro[i]);
            h8 v1 = *(const h8*)(hp + ro[i] + PLANE);
            h8 v2 = *(const h8*)(hp + ro[i] + 2 * PLANE);
            float cyi = cyw[i];
            r0 = fmaf(cyi, dot8f(v0, cwp), r0);
            r1 = fmaf(cyi, dot8f(v1, cwp), r1);
            r2 = fmaf(cyi, dot8f(v2, cwp), r2);
        }
    } else {
        pixel_slow(x, mw + ix, mh + iy, cxw, cyw, r0, r1, r2);
    }

    int oidx = mh * WW + mw;
    out[oidx] = r0;
    out[HW + oidx] = r1;
    out[2 * HW + oidx] = r2;
}

// fallback (f32 gathers only) if workspace is too small
__global__ __launch_bounds__(256) void warp_kernel_f32(const float* __restrict__ x,
                                                       const float* __restrict__ flow,
                                                       float* __restrict__ out) {
    int idx = blockIdx.x * blockDim.x + threadIdx.x;
    if (idx >= HW) return;
    int w = idx % WW;
    int h = idx / WW;
    float fx = flow[idx], fy = flow[HW + idx];
    float rfx = floorf(fx), rfy = floorf(fy);
    int bx = w + (int)rfx, by = h + (int)rfy;
    float cxw[8], cyw[8];
    sinc_weights(fx - rfx, cxw);
    sinc_weights(fy - rfy, cyw);
    float r0, r1, r2;
    pixel_slow(x, bx, by, cxw, cyw, r0, r1, r2);
    out[idx] = r0;
    out[HW + idx] = r1;
    out[2 * HW + idx] = r2;
}

extern "C" void kernel_launch(void* const* d_in, const int* in_sizes, int n_in,
                              void* d_out, int out_size, void* d_ws, size_t ws_size,
                              hipStream_t stream) {
    const float* x = (const float*)d_in[0];
    const float* flow = (const float*)d_in[1];
    float* out = (float*)d_out;

    if (ws_size >= WS_BYTES) {
        _Float16* ws = (_Float16*)d_ws;
        int nconv = CC * HH * (WW / 4);
        conv_kernel<<<(nconv + 255) / 256, 256, 0, stream>>>(x, ws);
        warp_kernel<<<NWG, 1024, 0, stream>>>(x, flow, ws, out);
    } else {
        warp_kernel_f32<<<(HW + 255) / 256, 256, 0, stream>>>(x, flow, out);
    }
}

// Round 7
// 50.539 us; speedup vs baseline: 1.3847x; 1.0671x over previous
//
#include <hip/hip_runtime.h>
#include <math.h>

#define CC 3
#define HH 720
#define WW 1280
#define HW (HH * WW)

// sorted-gather tiling: 64 wide x 8 tall per block, 512 threads, 1 px/thread
#define TW 64
#define TH 8
#define GX (WW / TW)    // 20
#define GY (HH / TH)    // 90
#define NWG (GX * GY)   // 1800 (div by 8 -> clean XCD swizzle)
#define NTHR 512

// fp16 workspace: copy A at even base, copy B at odd base (+1): any 8-tap
// window is ONE 4B-aligned global dwordx4. (proven round 3)
#define SW 1288
#define PLANE (HH * SW)
#define WS_HALFS (6 * PLANE + 8)
#define WS_BYTES ((size_t)WS_HALFS * 2)

#define RMAX 16                  // |floor(flow)| <= RMAX handled fast
#define NBY (TH + 2 * RMAX)      // 40 distinct base-row values
#define NKEY (NBY * 2 + 1)       // 81 (row,parity) buckets + slow bucket

typedef float f4 __attribute__((ext_vector_type(4), aligned(4)));
typedef _Float16 h8 __attribute__((ext_vector_type(8), aligned(4)));
typedef _Float16 h2v __attribute__((ext_vector_type(2)));

#if __has_builtin(__builtin_amdgcn_fdot2)
#define HAVE_FDOT2 1
#endif

// cos(pi*k/8), sin(pi*k/8), (-1)^k for k = -3..4 (index j = k+3)
__constant__ float COSK[8] = {0.38268343f, 0.70710678f, 0.92387953f, 1.0f,
                              0.92387953f, 0.70710678f, 0.38268343f, 0.0f};
__constant__ float SINK[8] = {-0.92387953f, -0.70710678f, -0.38268343f, 0.0f,
                              0.38268343f, 0.70710678f, 0.92387953f, 1.0f};
__constant__ float SGNK[8] = {-1.0f, 1.0f, -1.0f, 1.0f, -1.0f, 1.0f, -1.0f, 1.0f};

__device__ __forceinline__ void sinc_weights(float s, float* wgt) {
    const float PI = 3.14159265358979f;
    float sp = __sinf(PI * s);
    float s8, c8;
    __sincosf(PI * s * 0.125f, &s8, &c8);
#pragma unroll
    for (int j = 0; j < 8; ++j) {
        float t = s - (float)(j - 3);
        float win = c8 * COSK[j] + s8 * SINK[j];
        float r = (t == 0.0f) ? 1.0f : __fdividef(sp * SGNK[j], PI * t);
        wgt[j] = win * r;
    }
}

__device__ __forceinline__ float dot8f(h8 v, const h2v* cw) {
#ifdef HAVE_FDOT2
    h2v* p = (h2v*)&v;
    float a = __builtin_amdgcn_fdot2(p[0], cw[0], 0.0f, false);
    a = __builtin_amdgcn_fdot2(p[1], cw[1], a, false);
    a = __builtin_amdgcn_fdot2(p[2], cw[2], a, false);
    a = __builtin_amdgcn_fdot2(p[3], cw[3], a, false);
    return a;
#else
    float r = 0.f;
#pragma unroll
    for (int j = 0; j < 8; ++j)
        r = fmaf((float)v[j], (float)cw[j >> 1][j & 1], r);
    return r;
#endif
}

// x (f32 CHW) -> two fp16 copies in ws (even-base and odd-base)
__global__ __launch_bounds__(256) void conv_kernel(const float* __restrict__ x,
                                                   _Float16* __restrict__ ws) {
    int tid = blockIdx.x * blockDim.x + threadIdx.x;
    if (tid >= CC * HH * (WW / 4)) return;
    int k4 = tid % (WW / 4);
    int rest = tid / (WW / 4);
    int k = k4 * 4;
    f4 v = *(const f4*)(x + rest * WW + k);
    int dst = rest * SW + k;
    _Float16 a = (_Float16)v.x, b = (_Float16)v.y,
             c = (_Float16)v.z, d = (_Float16)v.w;
    typedef _Float16 h4 __attribute__((ext_vector_type(4), aligned(8)));
    *(h4*)(ws + dst) = (h4){a, b, c, d};
    _Float16* wb = ws + 3 * PLANE + 1 + dst;
    wb[0] = a; wb[1] = b; wb[2] = c; wb[3] = d;
}

// exact f32 global path (border / large-flow pixels) — full clamping
__device__ __forceinline__ void pixel_slow(const float* __restrict__ x,
                                           int bx, int by,
                                           const float* cxw, const float* cyw,
                                           float& r0, float& r1, float& r2) {
    int xcl[8];
#pragma unroll
    for (int j = 0; j < 8; ++j) xcl[j] = min(max(bx + (j - 3), 0), WW - 1);
    r0 = 0.f; r1 = 0.f; r2 = 0.f;
#pragma unroll
    for (int i = 0; i < 8; ++i) {
        int o = min(max(by + (i - 3), 0), HH - 1) * WW;
        float cyi = cyw[i];
        const float* p0 = x + o;
        const float* p1 = p0 + HW;
        const float* p2 = p1 + HW;
        float rs0 = 0.f, rs1 = 0.f, rs2 = 0.f;
#pragma unroll
        for (int j = 0; j < 8; ++j) {
            float cj = cxw[j];
            rs0 = fmaf(p0[xcl[j]], cj, rs0);
            rs1 = fmaf(p1[xcl[j]], cj, rs1);
            rs2 = fmaf(p2[xcl[j]], cj, rs2);
        }
        r0 = fmaf(cyi, rs0, r0);
        r1 = fmaf(cyi, rs1, r1);
        r2 = fmaf(cyi, rs2, r2);
    }
}

__global__ __launch_bounds__(NTHR) void warp_kernel(const float* __restrict__ x,
                                                    const float* __restrict__ flow,
                                                    const _Float16* __restrict__ hx,
                                                    float* __restrict__ out) {
    __shared__ float sfx[NTHR], sfy[NTHR];
    __shared__ unsigned short sid[NTHR];
    __shared__ int HIST[128], CUR[128];

    int tid = threadIdx.x;

    int bid = blockIdx.x;
    int swz = (bid & 7) * (NWG / 8) + (bid >> 3);   // NWG%8==0: bijective
    int tx = swz % GX;
    int ty = swz / GX;
    int w0 = tx * TW;
    int h0 = ty * TH;

    if (tid < 128) HIST[tid] = 0;

    // phase 1: load flow (coalesced)
    int w = w0 + (tid & 63);
    int h = h0 + (tid >> 6);
    int idx = h * WW + w;
    float fx = flow[idx];
    float fy = flow[HW + idx];
    sfx[tid] = fx;
    sfy[tid] = fy;
    __syncthreads();

    // key = (base row, parity) bucket; slow pixels -> tail bucket
    int key;
    {
        int ix = (int)floorf(fx), iy = (int)floorf(fy);
        int s = w + ix - 3;
        int by = h + iy;
        bool fast = (iy >= -RMAX) && (iy <= RMAX) && (s >= 0) && (s <= WW - 8);
        key = fast ? ((by - (h0 - RMAX)) * 2 + (s & 1)) : (NKEY - 1);
    }
    atomicAdd(&HIST[key], 1);
    __syncthreads();

    // phase 2: single-wave shuffle scan (2 buckets/lane over 128)
    if (tid < 64) {
        int a = HIST[2 * tid], b = HIST[2 * tid + 1];
        int sum = a + b;
#pragma unroll
        for (int d = 1; d < 64; d <<= 1) {
            int vv = __shfl_up(sum, d, 64);
            if (tid >= d) sum += vv;
        }
        int excl = sum - a - b;
        CUR[2 * tid] = excl;
        CUR[2 * tid + 1] = excl + a;
    }
    __syncthreads();

    // phase 3: scatter pixel ids into sorted order
    {
        int pos = atomicAdd(&CUR[key], 1);
        sid[pos] = (unsigned short)tid;
    }
    __syncthreads();

    // phase 4: process sorted pixel (lanes share rows -> L1 locality)
    int me = sid[tid];
    float mfx = sfx[me], mfy = sfy[me];
    int mw = w0 + (me & 63);
    int mh = h0 + (me >> 6);
    float rfx = floorf(mfx), rfy = floorf(mfy);
    float sx = mfx - rfx, sy = mfy - rfy;
    int ix = (int)rfx, iy = (int)rfy;
    int s = mw + ix - 3;
    int by = mh + iy;
    bool fast = (iy >= -RMAX) && (iy <= RMAX) && (s >= 0) && (s <= WW - 8);

    float r0, r1, r2;
    if (fast) {
        // addresses first, issue ch0 loads, THEN weights (hide latency)
        int ro[8];
#pragma unroll
        for (int i = 0; i < 8; ++i)
            ro[i] = min(max(by + (i - 3), 0), HH - 1) * SW;
        const _Float16* hp = hx + ((s & 1) ? (3 * PLANE + 1) : 0) + s;

        h8 v[8], u[8];
#pragma unroll
        for (int i = 0; i < 8; ++i) v[i] = *(const h8*)(hp + ro[i]);  // ch0

        float cxw[8], cyw[8];
        sinc_weights(sx, cxw);
        sinc_weights(sy, cyw);
        h2v cwp[4];
#pragma unroll
        for (int j = 0; j < 4; ++j)
            cwp[j] = (h2v){(_Float16)cxw[2 * j], (_Float16)cxw[2 * j + 1]};

        r0 = r1 = r2 = 0.f;
#pragma unroll
        for (int i = 0; i < 8; ++i) {       // issue ch1 while consuming ch0
            u[i] = *(const h8*)(hp + ro[i] + PLANE);
            r0 = fmaf(cyw[i], dot8f(v[i], cwp), r0);
        }
#pragma unroll
        for (int i = 0; i < 8; ++i) {       // issue ch2 while consuming ch1
            v[i] = *(const h8*)(hp + ro[i] + 2 * PLANE);
            r1 = fmaf(cyw[i], dot8f(u[i], cwp), r1);
        }
#pragma unroll
        for (int i = 0; i < 8; ++i)
            r2 = fmaf(cyw[i], dot8f(v[i], cwp), r2);
    } else {
        float cxw[8], cyw[8];
        sinc_weights(sx, cxw);
        sinc_weights(sy, cyw);
        pixel_slow(x, mw + ix, mh + iy, cxw, cyw, r0, r1, r2);
    }

    int oidx = mh * WW + mw;
    out[oidx] = r0;
    out[HW + oidx] = r1;
    out[2 * HW + oidx] = r2;
}

// fallback (f32 gathers only) if workspace is too small
__global__ __launch_bounds__(256) void warp_kernel_f32(const float* __restrict__ x,
                                                       const float* __restrict__ flow,
                                                       float* __restrict__ out) {
    int idx = blockIdx.x * blockDim.x + threadIdx.x;
    if (idx >= HW) return;
    int w = idx % WW;
    int h = idx / WW;
    float fx = flow[idx], fy = flow[HW + idx];
    float rfx = floorf(fx), rfy = floorf(fy);
    int bx = w + (int)rfx, by = h + (int)rfy;
    float cxw[8], cyw[8];
    sinc_weights(fx - rfx, cxw);
    sinc_weights(fy - rfy, cyw);
    float r0, r1, r2;
    pixel_slow(x, bx, by, cxw, cyw, r0, r1, r2);
    out[idx] = r0;
    out[HW + idx] = r1;
    out[2 * HW + idx] = r2;
}

extern "C" void kernel_launch(void* const* d_in, const int* in_sizes, int n_in,
                              void* d_out, int out_size, void* d_ws, size_t ws_size,
                              hipStream_t stream) {
    const float* x = (const float*)d_in[0];
    const float* flow = (const float*)d_in[1];
    float* out = (float*)d_out;

    if (ws_size >= WS_BYTES) {
        _Float16* ws = (_Float16*)d_ws;
        int nconv = CC * HH * (WW / 4);
        conv_kernel<<<(nconv + 255) / 256, 256, 0, stream>>>(x, ws);
        warp_kernel<<<NWG, NTHR, 0, stream>>>(x, flow, ws, out);
    } else {
        warp_kernel_f32<<<(HW + 255) / 256, 256, 0, stream>>>(x, flow, out);
    }
}

// Round 8
// 47.609 us; speedup vs baseline: 1.4699x; 1.0615x over previous
//
#include <hip/hip_runtime.h>
#include <math.h>

#define CC 3
#define HH 720
#define WW 1280
#define HW (HH * WW)

// sorted-gather tiling: 64 wide x 4 tall per block, 256 threads, 1 px/thread
#define TW 64
#define TH 4
#define GX (WW / TW)    // 20
#define GY (HH / TH)    // 180
#define NWG (GX * GY)   // 3600 (div by 8 -> clean XCD swizzle)
#define NTHR 256

// fp16 workspace: copy A at even base, copy B at odd base (+1): any 8-tap
// window is ONE 4B-aligned global dwordx4. (proven round 3)
#define SW 1288
#define PLANE (HH * SW)
#define WS_HALFS (6 * PLANE + 8)
#define WS_BYTES ((size_t)WS_HALFS * 2)

#define RMAX 16                      // |floor(flow)| <= RMAX handled fast
#define NBY (TH - 1 + 2 * RMAX + 1)  // 36 distinct base-row values
#define NKEY (NBY * 2 + 1)           // 73 (row,parity) buckets + slow bucket

typedef float f4 __attribute__((ext_vector_type(4), aligned(4)));
typedef _Float16 h8 __attribute__((ext_vector_type(8), aligned(4)));
typedef _Float16 h2v __attribute__((ext_vector_type(2)));

#if __has_builtin(__builtin_amdgcn_fdot2)
#define HAVE_FDOT2 1
#endif

// cos(pi*k/8), sin(pi*k/8), (-1)^k for k = -3..4 (index j = k+3)
__constant__ float COSK[8] = {0.38268343f, 0.70710678f, 0.92387953f, 1.0f,
                              0.92387953f, 0.70710678f, 0.38268343f, 0.0f};
__constant__ float SINK[8] = {-0.92387953f, -0.70710678f, -0.38268343f, 0.0f,
                              0.38268343f, 0.70710678f, 0.92387953f, 1.0f};
__constant__ float SGNK[8] = {-1.0f, 1.0f, -1.0f, 1.0f, -1.0f, 1.0f, -1.0f, 1.0f};

__device__ __forceinline__ void sinc_weights(float s, float* wgt) {
    const float PI = 3.14159265358979f;
    float sp = __sinf(PI * s);
    float s8, c8;
    __sincosf(PI * s * 0.125f, &s8, &c8);
#pragma unroll
    for (int j = 0; j < 8; ++j) {
        float t = s - (float)(j - 3);
        float win = c8 * COSK[j] + s8 * SINK[j];
        float r = (t == 0.0f) ? 1.0f : __fdividef(sp * SGNK[j], PI * t);
        wgt[j] = win * r;
    }
}

__device__ __forceinline__ float dot8f(h8 v, const h2v* cw) {
#ifdef HAVE_FDOT2
    h2v* p = (h2v*)&v;
    float a = __builtin_amdgcn_fdot2(p[0], cw[0], 0.0f, false);
    a = __builtin_amdgcn_fdot2(p[1], cw[1], a, false);
    a = __builtin_amdgcn_fdot2(p[2], cw[2], a, false);
    a = __builtin_amdgcn_fdot2(p[3], cw[3], a, false);
    return a;
#else
    float r = 0.f;
#pragma unroll
    for (int j = 0; j < 8; ++j)
        r = fmaf((float)v[j], (float)cw[j >> 1][j & 1], r);
    return r;
#endif
}

// x (f32 CHW) -> two fp16 copies in ws (even-base and odd-base)
__global__ __launch_bounds__(256) void conv_kernel(const float* __restrict__ x,
                                                   _Float16* __restrict__ ws) {
    int tid = blockIdx.x * blockDim.x + threadIdx.x;
    if (tid >= CC * HH * (WW / 4)) return;
    int k4 = tid % (WW / 4);
    int rest = tid / (WW / 4);
    int k = k4 * 4;
    f4 v = *(const f4*)(x + rest * WW + k);
    int dst = rest * SW + k;
    _Float16 a = (_Float16)v.x, b = (_Float16)v.y,
             c = (_Float16)v.z, d = (_Float16)v.w;
    typedef _Float16 h4 __attribute__((ext_vector_type(4), aligned(8)));
    *(h4*)(ws + dst) = (h4){a, b, c, d};
    _Float16* wb = ws + 3 * PLANE + 1 + dst;
    wb[0] = a; wb[1] = b; wb[2] = c; wb[3] = d;
}

// exact f32 global path (border / large-flow pixels) — full clamping
__device__ __forceinline__ void pixel_slow(const float* __restrict__ x,
                                           int bx, int by,
                                           const float* cxw, const float* cyw,
                                           float& r0, float& r1, float& r2) {
    int xcl[8];
#pragma unroll
    for (int j = 0; j < 8; ++j) xcl[j] = min(max(bx + (j - 3), 0), WW - 1);
    r0 = 0.f; r1 = 0.f; r2 = 0.f;
#pragma unroll
    for (int i = 0; i < 8; ++i) {
        int o = min(max(by + (i - 3), 0), HH - 1) * WW;
        float cyi = cyw[i];
        const float* p0 = x + o;
        const float* p1 = p0 + HW;
        const float* p2 = p1 + HW;
        float rs0 = 0.f, rs1 = 0.f, rs2 = 0.f;
#pragma unroll
        for (int j = 0; j < 8; ++j) {
            float cj = cxw[j];
            rs0 = fmaf(p0[xcl[j]], cj, rs0);
            rs1 = fmaf(p1[xcl[j]], cj, rs1);
            rs2 = fmaf(p2[xcl[j]], cj, rs2);
        }
        r0 = fmaf(cyi, rs0, r0);
        r1 = fmaf(cyi, rs1, r1);
        r2 = fmaf(cyi, rs2, r2);
    }
}

__global__ __launch_bounds__(NTHR) void warp_kernel(const float* __restrict__ x,
                                                    const float* __restrict__ flow,
                                                    const _Float16* __restrict__ hx,
                                                    float* __restrict__ out) {
    __shared__ float sfx[NTHR], sfy[NTHR];
    __shared__ unsigned short sid[NTHR];
    __shared__ int HIST[128], CUR[128];

    int tid = threadIdx.x;

    int bid = blockIdx.x;
    int swz = (bid & 7) * (NWG / 8) + (bid >> 3);   // NWG%8==0: bijective
    int tx = swz % GX;
    int ty = swz / GX;
    int w0 = tx * TW;
    int h0 = ty * TH;

    if (tid < 128) HIST[tid] = 0;

    // phase 1: load flow (coalesced)
    int w = w0 + (tid & 63);
    int h = h0 + (tid >> 6);
    int idx = h * WW + w;
    float fx = flow[idx];
    float fy = flow[HW + idx];
    sfx[tid] = fx;
    sfy[tid] = fy;
    __syncthreads();

    // key = (base row, parity) bucket; slow pixels -> tail bucket
    int key;
    {
        int ix = (int)floorf(fx), iy = (int)floorf(fy);
        int s = w + ix - 3;
        int by = h + iy;
        bool fast = (iy >= -RMAX) && (iy <= RMAX) && (s >= 0) && (s <= WW - 8);
        key = fast ? ((by - (h0 - RMAX)) * 2 + (s & 1)) : (NKEY - 1);
    }
    atomicAdd(&HIST[key], 1);
    __syncthreads();

    // phase 2: single-wave shuffle scan (2 buckets/lane over 128)
    if (tid < 64) {
        int a = HIST[2 * tid], b = HIST[2 * tid + 1];
        int sum = a + b;
#pragma unroll
        for (int d = 1; d < 64; d <<= 1) {
            int vv = __shfl_up(sum, d, 64);
            if (tid >= d) sum += vv;
        }
        int excl = sum - a - b;
        CUR[2 * tid] = excl;
        CUR[2 * tid + 1] = excl + a;
    }
    __syncthreads();

    // phase 3: scatter pixel ids into sorted order
    {
        int pos = atomicAdd(&CUR[key], 1);
        sid[pos] = (unsigned short)tid;
    }
    __syncthreads();

    // phase 4: process sorted pixel (lanes share rows -> L1 locality)
    int me = sid[tid];
    float mfx = sfx[me], mfy = sfy[me];
    int mw = w0 + (me & 63);
    int mh = h0 + (me >> 6);
    float rfx = floorf(mfx), rfy = floorf(mfy);
    float sx = mfx - rfx, sy = mfy - rfy;
    int ix = (int)rfx, iy = (int)rfy;
    int s = mw + ix - 3;
    int by = mh + iy;
    bool fast = (iy >= -RMAX) && (iy <= RMAX) && (s >= 0) && (s <= WW - 8);

    float r0, r1, r2;
    if (fast) {
        int ro[8];
#pragma unroll
        for (int i = 0; i < 8; ++i)
            ro[i] = min(max(by + (i - 3), 0), HH - 1) * SW;
        const _Float16* hp = hx + ((s & 1) ? (3 * PLANE + 1) : 0) + s;

        float cxw[8], cyw[8];
        sinc_weights(sx, cxw);
        sinc_weights(sy, cyw);
        h2v cwp[4];
#pragma unroll
        for (int j = 0; j < 4; ++j)
            cwp[j] = (h2v){(_Float16)cxw[2 * j], (_Float16)cxw[2 * j + 1]};

        r0 = r1 = r2 = 0.f;
#pragma unroll
        for (int i = 0; i < 8; ++i) {
            h8 v0 = *(const h8*)(hp + ro[i]);
            h8 v1 = *(const h8*)(hp + ro[i] + PLANE);
            h8 v2 = *(const h8*)(hp + ro[i] + 2 * PLANE);
            float cyi = cyw[i];
            r0 = fmaf(cyi, dot8f(v0, cwp), r0);
            r1 = fmaf(cyi, dot8f(v1, cwp), r1);
            r2 = fmaf(cyi, dot8f(v2, cwp), r2);
        }
    } else {
        float cxw[8], cyw[8];
        sinc_weights(sx, cxw);
        sinc_weights(sy, cyw);
        pixel_slow(x, mw + ix, mh + iy, cxw, cyw, r0, r1, r2);
    }

    int oidx = mh * WW + mw;
    out[oidx] = r0;
    out[HW + oidx] = r1;
    out[2 * HW + oidx] = r2;
}

// fallback (f32 gathers only) if workspace is too small
__global__ __launch_bounds__(256) void warp_kernel_f32(const float* __restrict__ x,
                                                       const float* __restrict__ flow,
                                                       float* __restrict__ out) {
    int idx = blockIdx.x * blockDim.x + threadIdx.x;
    if (idx >= HW) return;
    int w = idx % WW;
    int h = idx / WW;
    float fx = flow[idx], fy = flow[HW + idx];
    float rfx = floorf(fx), rfy = floorf(fy);
    int bx = w + (int)rfx, by = h + (int)rfy;
    float cxw[8], cyw[8];
    sinc_weights(fx - rfx, cxw);
    sinc_weights(fy - rfy, cyw);
    float r0, r1, r2;
    pixel_slow(x, bx, by, cxw, cyw, r0, r1, r2);
    out[idx] = r0;
    out[HW + idx] = r1;
    out[2 * HW + idx] = r2;
}

extern "C" void kernel_launch(void* const* d_in, const int* in_sizes, int n_in,
                              void* d_out, int out_size, void* d_ws, size_t ws_size,
                              hipStream_t stream) {
    const float* x = (const float*)d_in[0];
    const float* flow = (const float*)d_in[1];
    float* out = (float*)d_out;

    if (ws_size >= WS_BYTES) {
        _Float16* ws = (_Float16*)d_ws;
        int nconv = CC * HH * (WW / 4);
        conv_kernel<<<(nconv + 255) / 256, 256, 0, stream>>>(x, ws);
        warp_kernel<<<NWG, NTHR, 0, stream>>>(x, flow, ws, out);
    } else {
        warp_kernel_f32<<<(HW + 255) / 256, 256, 0, stream>>>(x, flow, out);
    }
}